// Round 2
// baseline (209.260 us; speedup 1.0000x reference)
//
#include <hip/hip_runtime.h>
#include <hip/hip_bf16.h>

#define B_ 2
#define S_ 4096
#define H_ 8
#define D_ 64
#define BQ 128     // q-rows per WG (4 waves x 32 rows, one 32x32 n-tile per wave)
#define BK 64

#define GLOBAL_AS __attribute__((address_space(1)))
#define LDS_AS    __attribute__((address_space(3)))

typedef short bf16x8 __attribute__((ext_vector_type(8)));
typedef short bf16x4 __attribute__((ext_vector_type(4)));
typedef float f32x4  __attribute__((ext_vector_type(4)));
typedef float f32x16 __attribute__((ext_vector_type(16)));
typedef unsigned int u32x4 __attribute__((ext_vector_type(4)));

// log2(e)/8: folded into Q so the exp path is a bare v_exp_f32
#define QSCALE 0.18033688011112043f

__device__ __forceinline__ short f2bf(float f) {
    __bf16 h = (__bf16)f;                 // RTNE
    return __builtin_bit_cast(short, h);
}

__device__ __forceinline__ bf16x8 pack8(float4 f0, float4 f1) {
    bf16x8 r;
    r[0]=f2bf(f0.x); r[1]=f2bf(f0.y); r[2]=f2bf(f0.z); r[3]=f2bf(f0.w);
    r[4]=f2bf(f1.x); r[5]=f2bf(f1.y); r[6]=f2bf(f1.z); r[7]=f2bf(f1.w);
    return r;
}

__device__ __forceinline__ bf16x8 pack8s(float4 f0, float4 f1, float s) {
    bf16x8 r;
    r[0]=f2bf(f0.x*s); r[1]=f2bf(f0.y*s); r[2]=f2bf(f0.z*s); r[3]=f2bf(f0.w*s);
    r[4]=f2bf(f1.x*s); r[5]=f2bf(f1.y*s); r[6]=f2bf(f1.z*s); r[7]=f2bf(f1.w*s);
    return r;
}

// packed bf16 pair (lo=a, hi=b); compiler fuses to v_cvt_pk_bf16_f32
__device__ __forceinline__ unsigned pkbf(float a, float b) {
    unsigned ua = (unsigned)(unsigned short)__builtin_bit_cast(unsigned short, (__bf16)a);
    unsigned ub = (unsigned)(unsigned short)__builtin_bit_cast(unsigned short, (__bf16)b);
    return ua | (ub << 16);
}

// v_permlane32_swap_b32 a, b :  a.hi <-> b.lo
//   a' = [a.lo | b.lo] (lanes 0-31 keep a, lanes 32-63 receive b's low half)
//   b' = [a.hi | b.hi] (lanes 0-31 receive a's high half, lanes 32-63 keep b)
// Direction pinned by the HW-verified T12 recipe: swap(pk(rows0,1), pk(rows8,9))
// yields both PV-frag words directly.
__device__ __forceinline__ void perm32swap(unsigned &a, unsigned &b) {
    asm("v_permlane32_swap_b32 %0, %1" : "+v"(a), "+v"(b));
}

// ---- fused pre-pass: role 0 = K fp32 [B,S,H,D] -> bf16 [B,H,S,D]
//                      role 1 = V fp32 [B,S,H,D] -> bf16 transposed [B,H,D,S]
__global__ __launch_bounds__(256) void cast_kv_kernel(
    const float* __restrict__ kin, const float* __restrict__ vin,
    unsigned short* __restrict__ kb, unsigned short* __restrict__ vtb)
{
    __shared__ float Lf[64][72];
    const int role = blockIdx.z & 1;
    const int b    = blockIdx.z >> 1;
    const int h    = blockIdx.y;
    const int s0   = blockIdx.x * 64;
    const int t    = threadIdx.x;

    if (role == 0) {
        int r = t >> 2, fq = t & 3;
        const float4* gp = (const float4*)(kin + (((size_t)(b*S_ + s0 + r)*H_ + h)*D_ + fq*16));
        bf16x8 o0 = pack8(gp[0], gp[1]);
        bf16x8 o1 = pack8(gp[2], gp[3]);
        unsigned short* ob = kb + ((size_t)(b*H_ + h)*S_ + s0 + r)*D_ + fq*16;
        *(bf16x8*)ob       = o0;
        *(bf16x8*)(ob + 8) = o1;
    } else {
        {
            int r  = t >> 2, fq = t & 3;
            const float4* gp = (const float4*)(vin + (((size_t)(b*S_ + s0 + r)*H_ + h)*D_ + fq*16));
            #pragma unroll
            for (int j = 0; j < 4; ++j)
                *(f32x4*)&Lf[r][fq*16 + 4*j] = (f32x4){gp[j].x, gp[j].y, gp[j].z, gp[j].w};
        }
        __syncthreads();
        {
            int d = t >> 2, sq = t & 3;
            bf16x8 o0, o1;
            #pragma unroll
            for (int j = 0; j < 8; ++j) o0[j] = f2bf(Lf[sq*16 + j][d]);
            #pragma unroll
            for (int j = 0; j < 8; ++j) o1[j] = f2bf(Lf[sq*16 + 8 + j][d]);
            unsigned short* ob = vtb + (((size_t)(b*H_ + h)*D_ + d)*S_ + s0 + sq*16);
            *(bf16x8*)(ob)     = o0;
            *(bf16x8*)(ob + 8) = o1;
        }
    }
}

// ---------------- main flash-attention kernel ----------------
// 32x32x16 MFMA restructure (R5/R6): wave owns one 32-q n-tile; S^T = K Q^T
// via 4 MFMAs per 32-key m-tile; P stays IN REGISTERS — cvt_pk_bf16 pairs +
// 4x v_permlane32_swap build the PV B-frags (keys hi*8+j lane-local), so the
// Ps LDS round-trip (8KB/wave-iter) is gone and aV traffic halves (1KB A-frag
// now feeds 32K FLOP). LDS traffic 4.8GB -> 2.6GB (was the binding pipe at
// ~59% of 118us). l via VALU adds on exp results + shfl_xor(32) at end
// (drops the 4 "ones" MFMAs). LDS 32KB -> 16KB/WG.
// R6 fix: permlane32_swap operand order matched to verified semantics
// (a.hi <-> b.lo): swap(pk0,pk2) etc., not swap(pk2,pk0).
// SPLIT: 2-way K-split, partial O^T + l to ws, combine kernel finishes.
template<bool SPLIT>
__global__ __launch_bounds__(256, 4) void fattn_kernel(
    const float* __restrict__ q, const unsigned short* __restrict__ kb,
    const unsigned short* __restrict__ vtb, float* __restrict__ out,
    float* __restrict__ Op, float* __restrict__ lw)
{
    __shared__ unsigned short Ks [BK][64];
    __shared__ unsigned short Vts[D_][64];

    const int tid  = threadIdx.x;
    const int wave = tid >> 6;
    const int lane = tid & 63;
    const int l31  = tid & 31;
    const int hi   = lane >> 5;
    const int h    = blockIdx.y;
    const int b    = SPLIT ? (blockIdx.z >> 1) : blockIdx.z;
    const int half = SPLIT ? (blockIdx.z & 1)  : 0;
    const int kt0  = half * 32;
    const int nkt  = SPLIT ? 32 : 64;
    const int q0   = blockIdx.x * BQ;
    const int bS   = b * S_;
    const int wq   = wave * 32;          // this wave's 32 q-rows

    // ---- A-frag LDS offsets (ushort units), tile-invariant, swizzled:
    // row = t*32 + l31, 8-elem chunk = (kc*2+hi) ^ (row&7); serves Ks and Vts
    int aoff[2][4];
    #pragma unroll
    for (int t = 0; t < 2; ++t)
        #pragma unroll
        for (int kc = 0; kc < 4; ++kc)
            aoff[t][kc] = (t*32 + l31)*64 + (((kc*2 + hi) ^ (l31 & 7))*8);

    // ---- staging lane mapping (slot = lane): 256 threads cover 64 rows x 64d
    const int srow = (lane >> 3);
    const int c8g  = (lane & 7) ^ srow;
    const int wqs  = wave * 16;                 // staging row base
    const unsigned short* ksg[2];
    const unsigned short* vtg[2];
    #pragma unroll
    for (int it = 0; it < 2; ++it) {
        int rk = wqs + it*8 + srow;
        ksg[it] = kb  + ((size_t)(b*H_ + h)*S_ + rk)*64 + c8g*8;
        vtg[it] = vtb + ((size_t)(b*H_ + h)*D_ + rk)*(size_t)S_ + c8g*8;
    }

    // ---- Q as B-frag of Q^T, pre-scaled: bq[kc], element j <-> d = kc*16+hi*8+j
    bf16x8 bq[4];
    {
        const int qrow = q0 + wq + l31;
        const float* qp = q + ((size_t)(bS + qrow)*H_ + h)*D_;
        #pragma unroll
        for (int kc = 0; kc < 4; ++kc) {
            const float4* q4 = (const float4*)(qp + kc*16 + hi*8);
            bq[kc] = pack8s(q4[0], q4[1], QSCALE);
        }
    }

    f32x16 oacc[2];
    #pragma unroll
    for (int dt = 0; dt < 2; ++dt)
        #pragma unroll
        for (int r = 0; r < 16; ++r) oacc[dt][r] = 0.f;
    float lp0 = 0.f, lp1 = 0.f;

    for (int i = 0; i < nkt; ++i) {
        const int kt = kt0 + i;
        __syncthreads();
        #pragma unroll
        for (int it = 0; it < 2; ++it) {
            __builtin_amdgcn_global_load_lds(
                (const GLOBAL_AS void*)(ksg[it] + (size_t)kt*BK*64),
                (LDS_AS void*)&Ks[wqs + it*8][0], 16, 0, 0);
            __builtin_amdgcn_global_load_lds(
                (const GLOBAL_AS void*)(vtg[it] + (size_t)kt*BK),
                (LDS_AS void*)&Vts[wqs + it*8][0], 16, 0, 0);
        }
        __syncthreads();

        #pragma unroll
        for (int mt = 0; mt < 2; ++mt) {
            // ---- S^T tile (32 keys x 32 q) = K Q^T : 4 MFMAs over D=64
            f32x16 s;
            #pragma unroll
            for (int r = 0; r < 16; ++r) s[r] = 0.f;
            #pragma unroll
            for (int kc = 0; kc < 4; ++kc) {
                bf16x8 aK = *(const bf16x8*)&Ks[0][aoff[mt][kc]];
                s = __builtin_amdgcn_mfma_f32_32x32x16_bf16(aK, bq[kc], s, 0,0,0);
            }

            // ---- P = exp2(S^T); l-partials; pack bf16 pairs (rows 2r,2r+1)
            // lane's s[r] = key (r&3)+8*(r>>2)+4*hi of this mt tile (q = l31)
            unsigned pk_[8];
            #pragma unroll
            for (int r = 0; r < 8; ++r) {
                float e0 = __builtin_exp2f(s[2*r]);
                float e1 = __builtin_exp2f(s[2*r+1]);
                lp0 += e0; lp1 += e1;
                pk_[r] = pkbf(e0, e1);
            }
            // ---- cross-half exchange -> PV B-frags (k = hi*8+j lane-local):
            // need w0=[pk0.lo|pk2.lo] w1=[pk1.lo|pk3.lo] w2=[pk0.hi|pk2.hi]
            //      w3=[pk1.hi|pk3.hi]; swap(a,b): a'=[a.lo|b.lo], b'=[a.hi|b.hi]
            perm32swap(pk_[0], pk_[2]);
            perm32swap(pk_[1], pk_[3]);
            perm32swap(pk_[4], pk_[6]);
            perm32swap(pk_[5], pk_[7]);
            u32x4 w0 = {pk_[0], pk_[1], pk_[2], pk_[3]};
            u32x4 w1 = {pk_[4], pk_[5], pk_[6], pk_[7]};
            bf16x8 bp0 = __builtin_bit_cast(bf16x8, w0);
            bf16x8 bp1 = __builtin_bit_cast(bf16x8, w1);

            // ---- O^T += V^T P^T (2 d-tiles x 2 key-chunks of this m-tile)
            #pragma unroll
            for (int dt = 0; dt < 2; ++dt) {
                bf16x8 aV0 = *(const bf16x8*)&Vts[0][aoff[dt][mt*2 + 0]];
                oacc[dt] = __builtin_amdgcn_mfma_f32_32x32x16_bf16(aV0, bp0, oacc[dt], 0,0,0);
                bf16x8 aV1 = *(const bf16x8*)&Vts[0][aoff[dt][mt*2 + 1]];
                oacc[dt] = __builtin_amdgcn_mfma_f32_32x32x16_bf16(aV1, bp1, oacc[dt], 0,0,0);
            }
        }
    }

    // ---- epilogue: l = own-half partial + partner-half partial
    float lt0 = lp0 + lp1;
    float lt  = lt0 + __shfl_xor(lt0, 32);
    const int orow = q0 + wq + l31;
    // oacc reg r of tile dt -> d = dt*32 + (r>>2)*8 + hi*4 + (r&3), col = q
    if constexpr (SPLIT) {
        float* ob = Op + (size_t)half*((size_t)B_*S_*H_*D_)
                       + ((size_t)(bS + orow)*H_ + h)*D_;
        #pragma unroll
        for (int dt = 0; dt < 2; ++dt)
            #pragma unroll
            for (int rg = 0; rg < 4; ++rg) {
                float4 o4 = { oacc[dt][rg*4+0], oacc[dt][rg*4+1],
                              oacc[dt][rg*4+2], oacc[dt][rg*4+3] };
                *(float4*)(ob + dt*32 + rg*8 + hi*4) = o4;
            }
        if (hi == 0)
            lw[(size_t)half*((size_t)B_*S_*H_) + (size_t)(bS + orow)*H_ + h] = lt;
    } else {
        const float linv = 1.0f / lt;
        float* ob = out + ((size_t)(bS + orow)*H_ + h)*D_;
        #pragma unroll
        for (int dt = 0; dt < 2; ++dt)
            #pragma unroll
            for (int rg = 0; rg < 4; ++rg) {
                float4 o4 = { oacc[dt][rg*4+0]*linv, oacc[dt][rg*4+1]*linv,
                              oacc[dt][rg*4+2]*linv, oacc[dt][rg*4+3]*linv };
                *(float4*)(ob + dt*32 + rg*8 + hi*4) = o4;
            }
    }
}

// ---- combine: out = (O0 + O1) / (l0 + l1)
__global__ __launch_bounds__(256) void combine_kernel(
    const float* __restrict__ Op, const float* __restrict__ lw,
    float* __restrict__ out)
{
    const size_t NR = (size_t)B_*S_*H_;
    const size_t NO = NR * D_;
    const int t = threadIdx.x;
    size_t r  = (size_t)blockIdx.x * 16 + (t >> 4);
    int   c4  = t & 15;
    const float4* p0 = (const float4*)(Op + r*D_) + c4;
    const float4* p1 = (const float4*)(Op + NO + r*D_) + c4;
    float linv = 1.0f / (lw[r] + lw[NR + r]);
    float4 a = *p0, b = *p1;
    float4 o = { (a.x+b.x)*linv, (a.y+b.y)*linv, (a.z+b.z)*linv, (a.w+b.w)*linv };
    *((float4*)(out + r*D_) + c4) = o;
}

// ---------------- fallback (round-2 style, no workspace) ----------------
#define FBQ 64
#define LDK 72
__global__ __launch_bounds__(256, 4) void fattn_fb(
    const float* __restrict__ q, const float* __restrict__ k,
    const float* __restrict__ v, float* __restrict__ out)
{
    __shared__ unsigned short Ks [BK][LDK];
    __shared__ unsigned short Vts[D_][LDK];
    __shared__ unsigned short Ps [FBQ][LDK];
    const int tid  = threadIdx.x;
    const int wave = tid >> 6;
    const int m16  = tid & 15;
    const int quad = (tid & 63) >> 4;
    const int h    = blockIdx.y;
    const int b    = blockIdx.z;
    const int q0   = blockIdx.x * FBQ;
    const int bS   = b * S_;
    const int wq   = wave * 16;
    bf16x8 bq[2];
    {
        const int qrow = q0 + wq + m16;
        const float* qb = q + ((size_t)(bS + qrow)*H_ + h)*D_;
        #pragma unroll
        for (int kh = 0; kh < 2; ++kh) {
            const float4* qp = (const float4*)(qb + kh*32 + quad*8);
            bq[kh] = pack8s(qp[0], qp[1], QSCALE);
        }
    }
    const short ONE = 0x3F80;
    bf16x8 ones = { ONE,ONE,ONE,ONE,ONE,ONE,ONE,ONE };
    f32x4 oacc[4];
    f32x4 lacc = (f32x4){0.f,0.f,0.f,0.f};
    #pragma unroll
    for (int dt = 0; dt < 4; ++dt) oacc[dt] = (f32x4){0.f,0.f,0.f,0.f};
    const int vd  = tid & 63;
    const int vkg = tid >> 6;
    for (int kt = 0; kt < S_/BK; ++kt) {
        const int k0 = kt * BK;
        __syncthreads();
        #pragma unroll
        for (int i = 0; i < 2; ++i) {
            int chunk = tid + i*256;
            int row = chunk >> 3, c8 = chunk & 7;
            const float4* gp = (const float4*)(k + ((size_t)(bS + k0 + row)*H_ + h)*D_ + c8*8);
            *(bf16x8*)&Ks[row][c8*8] = pack8(gp[0], gp[1]);
        }
        {
            const float* vb = v + ((size_t)(bS + k0 + vkg*16)*H_ + h)*D_ + vd;
            bf16x8 t0, t1;
            #pragma unroll
            for (int i = 0; i < 8; ++i) t0[i] = f2bf(vb[(size_t)i * (H_*D_)]);
            #pragma unroll
            for (int i = 0; i < 8; ++i) t1[i] = f2bf(vb[(size_t)(i+8) * (H_*D_)]);
            *(bf16x8*)&Vts[vd][vkg*16]     = t0;
            *(bf16x8*)&Vts[vd][vkg*16 + 8] = t1;
        }
        __syncthreads();
        f32x4 sacc[4];
        #pragma unroll
        for (int mt = 0; mt < 4; ++mt) sacc[mt] = (f32x4){0.f,0.f,0.f,0.f};
        #pragma unroll
        for (int kh = 0; kh < 2; ++kh)
            #pragma unroll
            for (int mt = 0; mt < 4; ++mt) {
                bf16x8 aK = *(const bf16x8*)&Ks[mt*16 + m16][kh*32 + quad*8];
                sacc[mt] = __builtin_amdgcn_mfma_f32_16x16x32_bf16(aK, bq[kh], sacc[mt], 0,0,0);
            }
        #pragma unroll
        for (int mt = 0; mt < 4; ++mt) {
            bf16x4 pk;
            #pragma unroll
            for (int r = 0; r < 4; ++r)
                pk[r] = f2bf(__builtin_exp2f(sacc[mt][r]));
            *(bf16x4*)&Ps[wq + m16][mt*16 + quad*4] = pk;
        }
        #pragma unroll
        for (int kh = 0; kh < 2; ++kh) {
            bf16x8 bp = *(const bf16x8*)&Ps[wq + m16][kh*32 + quad*8];
            lacc = __builtin_amdgcn_mfma_f32_16x16x32_bf16(ones, bp, lacc, 0,0,0);
            #pragma unroll
            for (int dt = 0; dt < 4; ++dt) {
                bf16x8 aV = *(const bf16x8*)&Vts[dt*16 + m16][kh*32 + quad*8];
                oacc[dt] = __builtin_amdgcn_mfma_f32_16x16x32_bf16(aV, bp, oacc[dt], 0,0,0);
            }
        }
    }
    const float linv = 1.0f / lacc[0];
    const int orow = q0 + wq + m16;
    float* ob = out + ((size_t)(bS + orow)*H_ + h)*D_;
    #pragma unroll
    for (int dt = 0; dt < 4; ++dt) {
        float4 o4 = { oacc[dt][0]*linv, oacc[dt][1]*linv,
                      oacc[dt][2]*linv, oacc[dt][3]*linv };
        *(float4*)(ob + dt*16 + quad*4) = o4;
    }
}

extern "C" void kernel_launch(void* const* d_in, const int* in_sizes, int n_in,
                              void* d_out, int out_size, void* d_ws, size_t ws_size,
                              hipStream_t stream) {
    const float* q = (const float*)d_in[0];
    const float* k = (const float*)d_in[1];
    const float* v = (const float*)d_in[2];
    float* out = (float*)d_out;
    const size_t elems = (size_t)B_*H_*S_*D_;                 // 4.19M
    const size_t NR    = (size_t)B_*S_*H_;                    // 65536
    const size_t need_cast  = 2 * elems * sizeof(unsigned short);
    const size_t need_split = need_cast + 2*elems*sizeof(float) + 2*NR*sizeof(float);

    if (ws_size >= need_split) {
        unsigned short* kb  = (unsigned short*)d_ws;
        unsigned short* vtb = kb + elems;
        float* Op = (float*)(vtb + elems);
        float* lw = Op + 2*elems;
        cast_kv_kernel<<<dim3(S_/64, H_, B_*2), dim3(256), 0, stream>>>(k, v, kb, vtb);
        fattn_kernel<true><<<dim3(S_/BQ, H_, B_*2), dim3(256), 0, stream>>>(
            q, kb, vtb, out, Op, lw);
        combine_kernel<<<dim3((int)(NR/16)), dim3(256), 0, stream>>>(Op, lw, out);
    } else if (ws_size >= need_cast) {
        unsigned short* kb  = (unsigned short*)d_ws;
        unsigned short* vtb = kb + elems;
        cast_kv_kernel<<<dim3(S_/64, H_, B_*2), dim3(256), 0, stream>>>(k, v, kb, vtb);
        fattn_kernel<false><<<dim3(S_/BQ, H_, B_), dim3(256), 0, stream>>>(
            q, kb, vtb, out, nullptr, nullptr);
    } else {
        fattn_fb<<<dim3(S_/FBQ, H_, B_), dim3(256), 0, stream>>>(q, k, v, out);
    }
}

// Round 3
// 206.007 us; speedup vs baseline: 1.0158x; 1.0158x over previous
//
#include <hip/hip_runtime.h>
#include <hip/hip_bf16.h>

#define B_ 2
#define S_ 4096
#define H_ 8
#define D_ 64
#define BQ 128     // q-rows per WG (4 waves x 32 rows, one 32x32 n-tile per wave)
#define BK 64

#define GLOBAL_AS __attribute__((address_space(1)))
#define LDS_AS    __attribute__((address_space(3)))

typedef short bf16x8 __attribute__((ext_vector_type(8)));
typedef short bf16x4 __attribute__((ext_vector_type(4)));
typedef float f32x4  __attribute__((ext_vector_type(4)));
typedef float f32x16 __attribute__((ext_vector_type(16)));
typedef unsigned int u32x4 __attribute__((ext_vector_type(4)));

// log2(e)/8: folded into Q so the exp path is a bare v_exp_f32
#define QSCALE 0.18033688011112043f

__device__ __forceinline__ short f2bf(float f) {
    __bf16 h = (__bf16)f;                 // RTNE
    return __builtin_bit_cast(short, h);
}

__device__ __forceinline__ bf16x8 pack8(float4 f0, float4 f1) {
    bf16x8 r;
    r[0]=f2bf(f0.x); r[1]=f2bf(f0.y); r[2]=f2bf(f0.z); r[3]=f2bf(f0.w);
    r[4]=f2bf(f1.x); r[5]=f2bf(f1.y); r[6]=f2bf(f1.z); r[7]=f2bf(f1.w);
    return r;
}

__device__ __forceinline__ bf16x8 pack8s(float4 f0, float4 f1, float s) {
    bf16x8 r;
    r[0]=f2bf(f0.x*s); r[1]=f2bf(f0.y*s); r[2]=f2bf(f0.z*s); r[3]=f2bf(f0.w*s);
    r[4]=f2bf(f1.x*s); r[5]=f2bf(f1.y*s); r[6]=f2bf(f1.z*s); r[7]=f2bf(f1.w*s);
    return r;
}

// packed bf16 pair (lo=a, hi=b); compiler fuses to v_cvt_pk_bf16_f32
__device__ __forceinline__ unsigned pkbf(float a, float b) {
    unsigned ua = (unsigned)(unsigned short)__builtin_bit_cast(unsigned short, (__bf16)a);
    unsigned ub = (unsigned)(unsigned short)__builtin_bit_cast(unsigned short, (__bf16)b);
    return ua | (ub << 16);
}

// v_permlane32_swap_b32 a, b :  a' = [a.lo | b.lo], b' = [a.hi | b.hi]
// (verified R6: swap(pk0,pk2) yields both PV-frag words directly)
__device__ __forceinline__ void perm32swap(unsigned &a, unsigned &b) {
    asm("v_permlane32_swap_b32 %0, %1" : "+v"(a), "+v"(b));
}

// ---- fused pre-pass: role 0 = K fp32 [B,S,H,D] -> bf16 [B,H,S,D]
//                      role 1 = V fp32 [B,S,H,D] -> bf16 transposed [B,H,D,S]
__global__ __launch_bounds__(256) void cast_kv_kernel(
    const float* __restrict__ kin, const float* __restrict__ vin,
    unsigned short* __restrict__ kb, unsigned short* __restrict__ vtb)
{
    __shared__ float Lf[64][72];
    const int role = blockIdx.z & 1;
    const int b    = blockIdx.z >> 1;
    const int h    = blockIdx.y;
    const int s0   = blockIdx.x * 64;
    const int t    = threadIdx.x;

    if (role == 0) {
        int r = t >> 2, fq = t & 3;
        const float4* gp = (const float4*)(kin + (((size_t)(b*S_ + s0 + r)*H_ + h)*D_ + fq*16));
        bf16x8 o0 = pack8(gp[0], gp[1]);
        bf16x8 o1 = pack8(gp[2], gp[3]);
        unsigned short* ob = kb + ((size_t)(b*H_ + h)*S_ + s0 + r)*D_ + fq*16;
        *(bf16x8*)ob       = o0;
        *(bf16x8*)(ob + 8) = o1;
    } else {
        {
            int r  = t >> 2, fq = t & 3;
            const float4* gp = (const float4*)(vin + (((size_t)(b*S_ + s0 + r)*H_ + h)*D_ + fq*16));
            #pragma unroll
            for (int j = 0; j < 4; ++j)
                *(f32x4*)&Lf[r][fq*16 + 4*j] = (f32x4){gp[j].x, gp[j].y, gp[j].z, gp[j].w};
        }
        __syncthreads();
        {
            int d = t >> 2, sq = t & 3;
            bf16x8 o0, o1;
            #pragma unroll
            for (int j = 0; j < 8; ++j) o0[j] = f2bf(Lf[sq*16 + j][d]);
            #pragma unroll
            for (int j = 0; j < 8; ++j) o1[j] = f2bf(Lf[sq*16 + 8 + j][d]);
            unsigned short* ob = vtb + (((size_t)(b*H_ + h)*D_ + d)*S_ + s0 + sq*16);
            *(bf16x8*)(ob)     = o0;
            *(bf16x8*)(ob + 8) = o1;
        }
    }
}

// ---------------- main flash-attention kernel ----------------
// R7: latency-bound fix. R6 counters showed no pipe >40% absolute; per-iter
// wall ~9.7k cyc vs ~3.5k of issue work — the binder was the serial
// {issue loads -> vmcnt(0)-drain barrier -> compute} chain (full L2/HBM
// latency per iter, zero overlap). Now: LDS double-buffer (2x16KB), loop =
// STAGE(next) -> s_waitcnt vmcnt(4) (counted, never 0 in loop) ->
// s_barrier -> compute(cur) -> s_barrier. Raw s_barrier (NOT __syncthreads,
// which forces a vmcnt(0) drain) + sched_barrier(0) fences (rule #18).
// setprio(1) around compute (T5; 4 independent WGs/SIMD give role diversity).
// Keeps R6's 32x32 in-register-P structure (16 LDS reads/iter, P never
// touches LDS; permlane32_swap builds PV B-frags).
// SPLIT: 2-way K-split, partial O^T + l to ws, combine kernel finishes.
template<bool SPLIT>
__global__ __launch_bounds__(256, 4) void fattn_kernel(
    const float* __restrict__ q, const unsigned short* __restrict__ kb,
    const unsigned short* __restrict__ vtb, float* __restrict__ out,
    float* __restrict__ Op, float* __restrict__ lw)
{
    __shared__ unsigned short Ks [2][BK][64];
    __shared__ unsigned short Vts[2][D_][64];

    const int tid  = threadIdx.x;
    const int wave = tid >> 6;
    const int lane = tid & 63;
    const int l31  = tid & 31;
    const int hi   = lane >> 5;
    const int h    = blockIdx.y;
    const int b    = SPLIT ? (blockIdx.z >> 1) : blockIdx.z;
    const int half = SPLIT ? (blockIdx.z & 1)  : 0;
    const int kt0  = half * 32;
    const int nkt  = SPLIT ? 32 : 64;
    const int q0   = blockIdx.x * BQ;
    const int bS   = b * S_;
    const int wq   = wave * 32;          // this wave's 32 q-rows

    // ---- A-frag LDS offsets (ushort units), tile-invariant, swizzled:
    // row = t*32 + l31, 8-elem chunk = (kc*2+hi) ^ (row&7); serves Ks and Vts
    int aoff[2][4];
    #pragma unroll
    for (int t = 0; t < 2; ++t)
        #pragma unroll
        for (int kc = 0; kc < 4; ++kc)
            aoff[t][kc] = (t*32 + l31)*64 + (((kc*2 + hi) ^ (l31 & 7))*8);

    // ---- staging lane mapping (slot = lane): 256 threads cover 64 rows x 64d
    const int srow = (lane >> 3);
    const int c8g  = (lane & 7) ^ srow;
    const int wqs  = wave * 16;                 // staging row base
    const unsigned short* ksg[2];
    const unsigned short* vtg[2];
    #pragma unroll
    for (int it = 0; it < 2; ++it) {
        int rk = wqs + it*8 + srow;
        ksg[it] = kb  + ((size_t)(b*H_ + h)*S_ + rk)*64 + c8g*8;
        vtg[it] = vtb + ((size_t)(b*H_ + h)*D_ + rk)*(size_t)S_ + c8g*8;
    }

    // ---- Q as B-frag of Q^T, pre-scaled: bq[kc], element j <-> d = kc*16+hi*8+j
    bf16x8 bq[4];
    {
        const int qrow = q0 + wq + l31;
        const float* qp = q + ((size_t)(bS + qrow)*H_ + h)*D_;
        #pragma unroll
        for (int kc = 0; kc < 4; ++kc) {
            const float4* q4 = (const float4*)(qp + kc*16 + hi*8);
            bq[kc] = pack8s(q4[0], q4[1], QSCALE);
        }
    }

    f32x16 oacc[2];
    #pragma unroll
    for (int dt = 0; dt < 2; ++dt)
        #pragma unroll
        for (int r = 0; r < 16; ++r) oacc[dt][r] = 0.f;
    float lp0 = 0.f, lp1 = 0.f;

    // ---- prologue: stage tile 0 into buffer 0 (4 loads in flight)
    #pragma unroll
    for (int it = 0; it < 2; ++it) {
        __builtin_amdgcn_global_load_lds(
            (const GLOBAL_AS void*)(ksg[it] + (size_t)kt0*BK*64),
            (LDS_AS void*)&Ks[0][wqs + it*8][0], 16, 0, 0);
        __builtin_amdgcn_global_load_lds(
            (const GLOBAL_AS void*)(vtg[it] + (size_t)kt0*BK),
            (LDS_AS void*)&Vts[0][wqs + it*8][0], 16, 0, 0);
    }

    for (int i = 0; i < nkt; ++i) {
        const int cur = i & 1;
        if (i + 1 < nkt) {
            // ---- stage next tile into the other buffer (protected by the
            // end-of-previous-iter barrier); loads stay in flight across compute
            const int kt = kt0 + i + 1;
            #pragma unroll
            for (int it = 0; it < 2; ++it) {
                __builtin_amdgcn_global_load_lds(
                    (const GLOBAL_AS void*)(ksg[it] + (size_t)kt*BK*64),
                    (LDS_AS void*)&Ks[cur ^ 1][wqs + it*8][0], 16, 0, 0);
                __builtin_amdgcn_global_load_lds(
                    (const GLOBAL_AS void*)(vtg[it] + (size_t)kt*BK),
                    (LDS_AS void*)&Vts[cur ^ 1][wqs + it*8][0], 16, 0, 0);
            }
            asm volatile("s_waitcnt vmcnt(4)" ::: "memory");   // current buf done
        } else {
            asm volatile("s_waitcnt vmcnt(0)" ::: "memory");   // drain last tile
        }
        __builtin_amdgcn_sched_barrier(0);
        __builtin_amdgcn_s_barrier();        // publish current buf to all waves
        __builtin_amdgcn_sched_barrier(0);

        __builtin_amdgcn_s_setprio(1);
        #pragma unroll
        for (int mt = 0; mt < 2; ++mt) {
            // ---- S^T tile (32 keys x 32 q) = K Q^T : 4 MFMAs over D=64
            f32x16 s;
            #pragma unroll
            for (int r = 0; r < 16; ++r) s[r] = 0.f;
            #pragma unroll
            for (int kc = 0; kc < 4; ++kc) {
                bf16x8 aK = *(const bf16x8*)&Ks[cur][0][aoff[mt][kc]];
                s = __builtin_amdgcn_mfma_f32_32x32x16_bf16(aK, bq[kc], s, 0,0,0);
            }

            // ---- P = exp2(S^T); l-partials; pack bf16 pairs (rows 2r,2r+1)
            unsigned pk_[8];
            #pragma unroll
            for (int r = 0; r < 8; ++r) {
                float e0 = __builtin_exp2f(s[2*r]);
                float e1 = __builtin_exp2f(s[2*r+1]);
                lp0 += e0; lp1 += e1;
                pk_[r] = pkbf(e0, e1);
            }
            // ---- cross-half exchange -> PV B-frags (k = hi*8+j lane-local)
            perm32swap(pk_[0], pk_[2]);
            perm32swap(pk_[1], pk_[3]);
            perm32swap(pk_[4], pk_[6]);
            perm32swap(pk_[5], pk_[7]);
            u32x4 w0 = {pk_[0], pk_[1], pk_[2], pk_[3]};
            u32x4 w1 = {pk_[4], pk_[5], pk_[6], pk_[7]};
            bf16x8 bp0 = __builtin_bit_cast(bf16x8, w0);
            bf16x8 bp1 = __builtin_bit_cast(bf16x8, w1);

            // ---- O^T += V^T P^T (2 d-tiles x 2 key-chunks of this m-tile)
            #pragma unroll
            for (int dt = 0; dt < 2; ++dt) {
                bf16x8 aV0 = *(const bf16x8*)&Vts[cur][0][aoff[dt][mt*2 + 0]];
                oacc[dt] = __builtin_amdgcn_mfma_f32_32x32x16_bf16(aV0, bp0, oacc[dt], 0,0,0);
                bf16x8 aV1 = *(const bf16x8*)&Vts[cur][0][aoff[dt][mt*2 + 1]];
                oacc[dt] = __builtin_amdgcn_mfma_f32_32x32x16_bf16(aV1, bp1, oacc[dt], 0,0,0);
            }
        }
        __builtin_amdgcn_s_setprio(0);
        __builtin_amdgcn_sched_barrier(0);
        __builtin_amdgcn_s_barrier();        // all waves done reading buf[cur]
    }

    // ---- epilogue: l = own-half partial + partner-half partial
    float lt0 = lp0 + lp1;
    float lt  = lt0 + __shfl_xor(lt0, 32);
    const int orow = q0 + wq + l31;
    // oacc reg r of tile dt -> d = dt*32 + (r>>2)*8 + hi*4 + (r&3), col = q
    if constexpr (SPLIT) {
        float* ob = Op + (size_t)half*((size_t)B_*S_*H_*D_)
                       + ((size_t)(bS + orow)*H_ + h)*D_;
        #pragma unroll
        for (int dt = 0; dt < 2; ++dt)
            #pragma unroll
            for (int rg = 0; rg < 4; ++rg) {
                float4 o4 = { oacc[dt][rg*4+0], oacc[dt][rg*4+1],
                              oacc[dt][rg*4+2], oacc[dt][rg*4+3] };
                *(float4*)(ob + dt*32 + rg*8 + hi*4) = o4;
            }
        if (hi == 0)
            lw[(size_t)half*((size_t)B_*S_*H_) + (size_t)(bS + orow)*H_ + h] = lt;
    } else {
        const float linv = 1.0f / lt;
        float* ob = out + ((size_t)(bS + orow)*H_ + h)*D_;
        #pragma unroll
        for (int dt = 0; dt < 2; ++dt)
            #pragma unroll
            for (int rg = 0; rg < 4; ++rg) {
                float4 o4 = { oacc[dt][rg*4+0]*linv, oacc[dt][rg*4+1]*linv,
                              oacc[dt][rg*4+2]*linv, oacc[dt][rg*4+3]*linv };
                *(float4*)(ob + dt*32 + rg*8 + hi*4) = o4;
            }
    }
}

// ---- combine: out = (O0 + O1) / (l0 + l1)
__global__ __launch_bounds__(256) void combine_kernel(
    const float* __restrict__ Op, const float* __restrict__ lw,
    float* __restrict__ out)
{
    const size_t NR = (size_t)B_*S_*H_;
    const size_t NO = NR * D_;
    const int t = threadIdx.x;
    size_t r  = (size_t)blockIdx.x * 16 + (t >> 4);
    int   c4  = t & 15;
    const float4* p0 = (const float4*)(Op + r*D_) + c4;
    const float4* p1 = (const float4*)(Op + NO + r*D_) + c4;
    float linv = 1.0f / (lw[r] + lw[NR + r]);
    float4 a = *p0, b = *p1;
    float4 o = { (a.x+b.x)*linv, (a.y+b.y)*linv, (a.z+b.z)*linv, (a.w+b.w)*linv };
    *((float4*)(out + r*D_) + c4) = o;
}

// ---------------- fallback (round-2 style, no workspace) ----------------
#define FBQ 64
#define LDK 72
__global__ __launch_bounds__(256, 4) void fattn_fb(
    const float* __restrict__ q, const float* __restrict__ k,
    const float* __restrict__ v, float* __restrict__ out)
{
    __shared__ unsigned short Ks [BK][LDK];
    __shared__ unsigned short Vts[D_][LDK];
    __shared__ unsigned short Ps [FBQ][LDK];
    const int tid  = threadIdx.x;
    const int wave = tid >> 6;
    const int m16  = tid & 15;
    const int quad = (tid & 63) >> 4;
    const int h    = blockIdx.y;
    const int b    = blockIdx.z;
    const int q0   = blockIdx.x * FBQ;
    const int bS   = b * S_;
    const int wq   = wave * 16;
    bf16x8 bq[2];
    {
        const int qrow = q0 + wq + m16;
        const float* qb = q + ((size_t)(bS + qrow)*H_ + h)*D_;
        #pragma unroll
        for (int kh = 0; kh < 2; ++kh) {
            const float4* qp = (const float4*)(qb + kh*32 + quad*8);
            bq[kh] = pack8s(qp[0], qp[1], QSCALE);
        }
    }
    const short ONE = 0x3F80;
    bf16x8 ones = { ONE,ONE,ONE,ONE,ONE,ONE,ONE,ONE };
    f32x4 oacc[4];
    f32x4 lacc = (f32x4){0.f,0.f,0.f,0.f};
    #pragma unroll
    for (int dt = 0; dt < 4; ++dt) oacc[dt] = (f32x4){0.f,0.f,0.f,0.f};
    const int vd  = tid & 63;
    const int vkg = tid >> 6;
    for (int kt = 0; kt < S_/BK; ++kt) {
        const int k0 = kt * BK;
        __syncthreads();
        #pragma unroll
        for (int i = 0; i < 2; ++i) {
            int chunk = tid + i*256;
            int row = chunk >> 3, c8 = chunk & 7;
            const float4* gp = (const float4*)(k + ((size_t)(bS + k0 + row)*H_ + h)*D_ + c8*8);
            *(bf16x8*)&Ks[row][c8*8] = pack8(gp[0], gp[1]);
        }
        {
            const float* vb = v + ((size_t)(bS + k0 + vkg*16)*H_ + h)*D_ + vd;
            bf16x8 t0, t1;
            #pragma unroll
            for (int i = 0; i < 8; ++i) t0[i] = f2bf(vb[(size_t)i * (H_*D_)]);
            #pragma unroll
            for (int i = 0; i < 8; ++i) t1[i] = f2bf(vb[(size_t)(i+8) * (H_*D_)]);
            *(bf16x8*)&Vts[vd][vkg*16]     = t0;
            *(bf16x8*)&Vts[vd][vkg*16 + 8] = t1;
        }
        __syncthreads();
        f32x4 sacc[4];
        #pragma unroll
        for (int mt = 0; mt < 4; ++mt) sacc[mt] = (f32x4){0.f,0.f,0.f,0.f};
        #pragma unroll
        for (int kh = 0; kh < 2; ++kh)
            #pragma unroll
            for (int mt = 0; mt < 4; ++mt) {
                bf16x8 aK = *(const bf16x8*)&Ks[mt*16 + m16][kh*32 + quad*8];
                sacc[mt] = __builtin_amdgcn_mfma_f32_16x16x32_bf16(aK, bq[kh], sacc[mt], 0,0,0);
            }
        #pragma unroll
        for (int mt = 0; mt < 4; ++mt) {
            bf16x4 pk;
            #pragma unroll
            for (int r = 0; r < 4; ++r)
                pk[r] = f2bf(__builtin_exp2f(sacc[mt][r]));
            *(bf16x4*)&Ps[wq + m16][mt*16 + quad*4] = pk;
        }
        #pragma unroll
        for (int kh = 0; kh < 2; ++kh) {
            bf16x8 bp = *(const bf16x8*)&Ps[wq + m16][kh*32 + quad*8];
            lacc = __builtin_amdgcn_mfma_f32_16x16x32_bf16(ones, bp, lacc, 0,0,0);
            #pragma unroll
            for (int dt = 0; dt < 4; ++dt) {
                bf16x8 aV = *(const bf16x8*)&Vts[dt*16 + m16][kh*32 + quad*8];
                oacc[dt] = __builtin_amdgcn_mfma_f32_16x16x32_bf16(aV, bp, oacc[dt], 0,0,0);
            }
        }
    }
    const float linv = 1.0f / lacc[0];
    const int orow = q0 + wq + m16;
    float* ob = out + ((size_t)(bS + orow)*H_ + h)*D_;
    #pragma unroll
    for (int dt = 0; dt < 4; ++dt) {
        float4 o4 = { oacc[dt][0]*linv, oacc[dt][1]*linv,
                      oacc[dt][2]*linv, oacc[dt][3]*linv };
        *(float4*)(ob + dt*16 + quad*4) = o4;
    }
}

extern "C" void kernel_launch(void* const* d_in, const int* in_sizes, int n_in,
                              void* d_out, int out_size, void* d_ws, size_t ws_size,
                              hipStream_t stream) {
    const float* q = (const float*)d_in[0];
    const float* k = (const float*)d_in[1];
    const float* v = (const float*)d_in[2];
    float* out = (float*)d_out;
    const size_t elems = (size_t)B_*H_*S_*D_;                 // 4.19M
    const size_t NR    = (size_t)B_*S_*H_;                    // 65536
    const size_t need_cast  = 2 * elems * sizeof(unsigned short);
    const size_t need_split = need_cast + 2*elems*sizeof(float) + 2*NR*sizeof(float);

    if (ws_size >= need_split) {
        unsigned short* kb  = (unsigned short*)d_ws;
        unsigned short* vtb = kb + elems;
        float* Op = (float*)(vtb + elems);
        float* lw = Op + 2*elems;
        cast_kv_kernel<<<dim3(S_/64, H_, B_*2), dim3(256), 0, stream>>>(k, v, kb, vtb);
        fattn_kernel<true><<<dim3(S_/BQ, H_, B_*2), dim3(256), 0, stream>>>(
            q, kb, vtb, out, Op, lw);
        combine_kernel<<<dim3((int)(NR/16)), dim3(256), 0, stream>>>(Op, lw, out);
    } else if (ws_size >= need_cast) {
        unsigned short* kb  = (unsigned short*)d_ws;
        unsigned short* vtb = kb + elems;
        cast_kv_kernel<<<dim3(S_/64, H_, B_*2), dim3(256), 0, stream>>>(k, v, kb, vtb);
        fattn_kernel<false><<<dim3(S_/BQ, H_, B_), dim3(256), 0, stream>>>(
            q, kb, vtb, out, nullptr, nullptr);
    } else {
        fattn_fb<<<dim3(S_/FBQ, H_, B_), dim3(256), 0, stream>>>(q, k, v, out);
    }
}